// Round 5
// baseline (503.971 us; speedup 1.0000x reference)
//
#include <hip/hip_runtime.h>
#include <hip/hip_bf16.h>
#include <stdint.h>

// GAT forward, N=8192, IN=256, OUT=128. Inputs fp32 (adj int32), output fp32.
// softmax_j(a1_i + a2_j | adj) == adj_ij*exp(a2_j)/sum_j adj_ij*exp(a2_j)  (a1 cancels)
// -> out = (adj @ (w*h)) / (adj @ w), with w=exp(h.a2w+a2b), h=F@W+b.
// v8: k_agg occupancy fix. R1-R4 showed k_agg invariant (~135-175us) to A-format,
// B-layout, atomics, and grid size -> the real cap was 72 accumulator AGPRs
// (unified file: 116 VGPR + 72 AGPR ~= 188 -> 2 waves/SIMD; rocprof VGPR_Count
// excludes AGPRs). Wave now owns 16 rows (acc[9] = 36 AGPR, ~116 total regs)
// with __launch_bounds__(256,4) -> 4 waves/SIMD, 2x latency-hiding.
//   k_adjbits: adj int32 -> 8 MB bitmask (int4/lane loads + shuffle pack).
//   k_hW:      h/w/whB VALU kernel (unchanged this round).
//   k_agg:     bitmask x fragment-major whB -> per-wave partials (no atomics).
//   k_epi:     reduce 16 ksplit-partials + divide (re-indexed for 16-row waves).

typedef __attribute__((ext_vector_type(8))) short short8;
typedef __attribute__((ext_vector_type(4))) float float4v;

static __device__ __forceinline__ unsigned short f2bf(float f) {
    union { float f; uint32_t i; } v; v.f = f;
    uint32_t r = v.i + 0x7FFFu + ((v.i >> 16) & 1u);
    return (unsigned short)(r >> 16);
}

// round fp32 to bf16 precision, keep as fp32 (matches MFMA-bf16 numerics)
static __device__ __forceinline__ float bfr(float x) {
    union { float f; uint32_t u; } v; v.f = x;
    uint32_t r = (v.u + 0x7FFFu + ((v.u >> 16) & 1u)) & 0xFFFF0000u;
    union { uint32_t u; float f; } o; o.u = r;
    return o.f;
}

// expand 8 bits -> 8 packed bf16 {0.0, 1.0}.
static __device__ __forceinline__ short8 expand8(uint32_t B) {
    uint64_t S = ((uint64_t)B * 0x8040201008040201ull >> 7) & 0x0101010101010101ull;
    uint32_t lo = (uint32_t)S;          // bytes {b7,b6,b5,b4}
    uint32_t hi = (uint32_t)(S >> 32);  // bytes {b3,b2,b1,b0}
    union { uint32_t u[4]; short8 s; } r;
    r.u[0] = ((hi >> 24) | (((hi >> 16) & 0xFFu) << 16)) * 0x3F80u;  // e0,e1
    r.u[1] = (((hi >> 8) & 0xFFu) | ((hi & 0xFFu) << 16)) * 0x3F80u; // e2,e3
    r.u[2] = ((lo >> 24) | (((lo >> 16) & 0xFFu) << 16)) * 0x3F80u;  // e4,e5
    r.u[3] = (((lo >> 8) & 0xFFu) | ((lo & 0xFFu) << 16)) * 0x3F80u; // e6,e7
    return r.s;
}

// ---- prepass: adj int32 -> bitmask. 4096 blocks x 256 (wave = half a row). ----
__global__ __launch_bounds__(256) void k_adjbits(const int* __restrict__ adj,
                                                 uint32_t* __restrict__ adjb) {
    int t = threadIdx.x, lane = t & 63;
    int wv = blockIdx.x * 4 + (t >> 6);           // 0..16383
    int row = wv >> 1, half = wv & 1;
    const int4* p = reinterpret_cast<const int4*>(adj + (size_t)row * 8192 + half * 4096) + lane;
    uint32_t* ob = adjb + (size_t)row * 256 + half * 128;
    #pragma unroll 4
    for (int kk = 0; kk < 16; kk++) {
        int4 v = p[kk * 64];
        uint32_t nib = (v.x != 0 ? 1u : 0u) | (v.y != 0 ? 2u : 0u) |
                       (v.z != 0 ? 4u : 0u) | (v.w != 0 ? 8u : 0u);
        uint32_t q = nib | (((uint32_t)__shfl_xor((int)nib, 1)) << 4);
        q |= ((uint32_t)__shfl_xor((int)q, 2)) << 8;
        q |= ((uint32_t)__shfl_xor((int)q, 4)) << 16;
        if ((lane & 7) == 0) ob[kk * 8 + (lane >> 3)] = q;
    }
}

// ---- h = F@W+b, w = exp(h.a2w+a2b), emit fragment-major whB ----
__global__ __launch_bounds__(256) void k_hW(const float* __restrict__ F,
                                            const float* __restrict__ W,
                                            const float* __restrict__ bvec,
                                            const float* __restrict__ a2w,
                                            const float* __restrict__ a2b,
                                            unsigned short* __restrict__ whB) {
    __shared__ float Fs[32 * 256];     // 32 KB
    __shared__ float Ws[64 * 128];     // 32 KB (one kt-chunk of W)
    __shared__ float bs[128], aws[128], wls[32];
    __shared__ float ab_s;

    int t = threadIdx.x;
    int row = t >> 3, g = t & 7;
    int ig = blockIdx.x, j0 = ig * 32;

    if (t < 128) { bs[t] = bvec[t]; aws[t] = a2w[t]; }
    if (t == 0) ab_s = a2b[0];

    #pragma unroll
    for (int i = 0; i < 8; i++) {
        int flat = t + 256 * i;                   // float4 index
        int fr = flat >> 6, fp_ = (flat & 63) << 2;
        float4 v = *reinterpret_cast<const float4*>(F + (size_t)(j0 + fr) * 256 + fp_);
        float4 o; o.x = bfr(v.x); o.y = bfr(v.y); o.z = bfr(v.z); o.w = bfr(v.w);
        *reinterpret_cast<float4*>(&Fs[fr * 256 + fp_]) = o;
    }

    float h[16];
    #pragma unroll
    for (int i = 0; i < 16; i++) h[i] = 0.0f;

    for (int kt = 0; kt < 4; kt++) {
        if (kt) __syncthreads();
        #pragma unroll
        for (int i = 0; i < 8; i++) {
            int flat = t + 256 * i;
            int wr = flat >> 5, wp = (flat & 31) << 2;
            float4 v = *reinterpret_cast<const float4*>(W + (size_t)(kt * 64 + wr) * 128 + wp);
            float4 o; o.x = bfr(v.x); o.y = bfr(v.y); o.z = bfr(v.z); o.w = bfr(v.w);
            *reinterpret_cast<float4*>(&Ws[wr * 128 + wp]) = o;
        }
        __syncthreads();
        for (int kk = 0; kk < 64; kk++) {
            float f = Fs[row * 256 + kt * 64 + kk];
            #pragma unroll
            for (int i = 0; i < 16; i++)
                h[i] += f * Ws[kk * 128 + g * 16 + i];
        }
    }

    float part = 0.0f;
    #pragma unroll
    for (int i = 0; i < 16; i++) {
        h[i] += bs[g * 16 + i];
        part += h[i] * aws[g * 16 + i];
    }
    part += __shfl_xor(part, 1);
    part += __shfl_xor(part, 2);
    part += __shfl_xor(part, 4);
    float wv = expf(fminf(fmaxf(part + ab_s, -60.0f), 60.0f));
    if (g == 0) wls[row] = wv;

    // whB record (ig,c): lane l=(kq,m), elem r holds B[k=ig*32+kq*8+r][c*16+m].
    int kq = row >> 3, r = row & 7;
    #pragma unroll
    for (int i = 0; i < 16; i++) {
        unsigned short u = f2bf(h[i] * wv);
        whB[((size_t)(ig * 9 + g) * 64 + kq * 16 + i) * 8 + r] = u;
    }
    __syncthreads();
    if (t < 64) {
        int m0 = t & 15, kq2 = t >> 4;
        uint4 val = make_uint4(0u, 0u, 0u, 0u);
        if (m0 == 0) {
            uint32_t u0 = (uint32_t)f2bf(wls[kq2 * 8 + 0]) | ((uint32_t)f2bf(wls[kq2 * 8 + 1]) << 16);
            uint32_t u1 = (uint32_t)f2bf(wls[kq2 * 8 + 2]) | ((uint32_t)f2bf(wls[kq2 * 8 + 3]) << 16);
            uint32_t u2 = (uint32_t)f2bf(wls[kq2 * 8 + 4]) | ((uint32_t)f2bf(wls[kq2 * 8 + 5]) << 16);
            uint32_t u3 = (uint32_t)f2bf(wls[kq2 * 8 + 6]) | ((uint32_t)f2bf(wls[kq2 * 8 + 7]) << 16);
            val = make_uint4(u0, u1, u2, u3);
        }
        *reinterpret_cast<uint4*>(whB + ((size_t)(ig * 9 + 8) * 64 + t) * 8) = val;
    }
}

// ---- KMAIN v8: 16-row waves, 4 waves/SIMD ----
// 2048 blocks x 4 waves = 8192 waves; wave = (rowset 16 rows, ksplit K-chunk 512).
// acc[9] = 36 AGPR; total regs ~116 -> launch_bounds(.,4) holds 4 waves/SIMD.
// P[wid][36][64]: 36 coalesced 256 B stores per wave.
__global__ __launch_bounds__(256, 4) void k_agg(const uint32_t* __restrict__ adjb,
                                                const unsigned short* __restrict__ whB,
                                                float* __restrict__ P) {
    int t = threadIdx.x;
    int wid = blockIdx.x * 4 + (t >> 6);          // 0..8191
    int lane = t & 63;
    int m = lane & 15, kq = lane >> 4;
    int rowset = wid >> 4, ksplit = wid & 15;     // 512 rowsets x 16 ksplits
    int rb = rowset * 16;

    float4v acc[9];
    #pragma unroll
    for (int c = 0; c < 9; c++) acc[c] = (float4v)0.0f;

    const uint32_t* w0 = adjb + (size_t)(rb + m) * 256 + ksplit * 16;
    const unsigned short* bp = whB + ((size_t)(ksplit * 16) * 576 + (size_t)lane) * 8;
    uint32_t sh = kq * 8;

    #pragma unroll 4
    for (int i = 0; i < 16; i++) {
        uint32_t U0 = w0[i];
        short8 af0 = expand8((U0 >> sh) & 0xFFu);
        #pragma unroll
        for (int c = 0; c < 9; c++) {
            short8 bf = *reinterpret_cast<const short8*>(bp + (size_t)i * 4608 + c * 512);
            acc[c] = __builtin_amdgcn_mfma_f32_16x16x32_bf16(af0, bf, acc[c], 0, 0, 0);
        }
    }

    float* o = P + (size_t)wid * 2304 + lane;
    #pragma unroll
    for (int c = 0; c < 9; c++)
        for (int rr = 0; rr < 4; rr++)
            o[(c * 4 + rr) * 64] = acc[c][rr];
}

// ---- reduce 16 ksplit-partials + divide. 512 blocks (one 16-row rowset each). ----
__global__ __launch_bounds__(256) void k_epi(const float* __restrict__ P,
                                             float* __restrict__ out) {
    __shared__ float den[16];
    int t = threadIdx.x;
    int g = blockIdx.x;
    const float* base = P + (size_t)g * 16 * 2304;

    float r[9];
    #pragma unroll
    for (int i = 0; i < 9; i++) {
        float s = 0.0f;
        #pragma unroll 4
        for (int ks = 0; ks < 16; ks++)
            s += base[(size_t)ks * 2304 + t + 256 * i];
        r[i] = s;
        int p = t + 256 * i;
        int instr = p >> 6, lane = p & 63;
        int c = instr >> 2, rr = instr & 3;
        int m = lane & 15, kq = lane >> 4;
        if (c == 8 && m == 0) den[kq * 4 + rr] = s;
    }
    __syncthreads();
    #pragma unroll
    for (int i = 0; i < 9; i++) {
        int p = t + 256 * i;
        int instr = p >> 6, lane = p & 63;
        int c = instr >> 2, rr = instr & 3;
        int m = lane & 15, kq = lane >> 4;
        if (c < 8) {
            int jl = kq * 4 + rr;
            out[((size_t)(g * 16 + jl)) * 128 + c * 16 + m] = r[i] / den[jl];
        }
    }
}

extern "C" void kernel_launch(void* const* d_in, const int* in_sizes, int n_in,
                              void* d_out, int out_size, void* d_ws, size_t ws_size,
                              hipStream_t stream) {
    const float* F   = (const float*)d_in[0];     // [8192][256]
    const int*   adj = (const int*)d_in[1];       // [8192][8192] 0/1
    const float* W   = (const float*)d_in[2];     // [256][128]
    const float* bv  = (const float*)d_in[3];     // [128]
    const float* a2w = (const float*)d_in[6];     // [128]  (a1 cancels; d_in[4],[5] unused)
    const float* a2b = (const float*)d_in[7];     // [1]
    float* out = (float*)d_out;                   // [8192][128]

    char* ws = (char*)d_ws;
    unsigned short* whB  = (unsigned short*)(ws);            //  2,359,296 B
    uint32_t*       adjb = (uint32_t*)(ws + 2359296);        //  8,388,608 B
    float*          P    = (float*)(ws + 10747904);          // 75,497,472 B (8192 x 2304 fp32)
                                                             // total 86,245,376

    k_hW<<<256, 256, 0, stream>>>(F, W, bv, a2w, a2b, whB);
    k_adjbits<<<4096, 256, 0, stream>>>(adj, adjb);
    k_agg<<<2048, 256, 0, stream>>>(adjb, whB, P);
    k_epi<<<512, 256, 0, stream>>>(P, out);
}

// Round 6
// 430.889 us; speedup vs baseline: 1.1696x; 1.1696x over previous
//
#include <hip/hip_runtime.h>
#include <hip/hip_bf16.h>
#include <stdint.h>

// GAT forward, N=8192, IN=256, OUT=128. Inputs fp32 (adj int32), output fp32.
// softmax_j(a1_i + a2_j | adj) == adj_ij*exp(a2_j)/sum_j adj_ij*exp(a2_j)  (a1 cancels)
// -> out = (adj @ (w*h)) / (adj @ w), with w=exp(h.a2w+a2b), h=F@W+b.
// v9: LDS-staged k_agg (guide §5 canonical structure). R0-R5 evidence: k_agg was
// ~150-200us across every A-format/B-layout/atomic/grid variant with ALL pipes idle
// (Mfma 4%, VALU 5%, HBM 16%) -> per-wave VMEM ILP strangled by regalloc (acc 72
// + addressing leaves no room for in-flight B-frags; ~0.3 loads outstanding by
// Little's law). Fix: global_load_lds (width 16) double-buffered staging of the
// fragment-major whB chunk + mask chunk; compute reads ds_read_b128 (latency
// hideable at 2 waves/SIMD). 512 blocks = 2 blocks/CU resident (LDS 77.8 KB),
// blocks sharing a ksplit B-chunk land on one XCD (blk%8) -> natural L2 locality.
//   k_hW:      h/w/whB VALU kernel (unchanged, R4-proven).
//   k_adjbits: adj int32 -> 8 MB bitmask (unchanged, R4-proven).
//   k_agg:     LDS-staged bitmask x whB -> per-wave partials P (8 ksplits).
//   k_epi:     reduce 8 ksplit-partials + divide.

typedef __attribute__((ext_vector_type(8))) short short8;
typedef __attribute__((ext_vector_type(4))) float float4v;

static __device__ __forceinline__ unsigned short f2bf(float f) {
    union { float f; uint32_t i; } v; v.f = f;
    uint32_t r = v.i + 0x7FFFu + ((v.i >> 16) & 1u);
    return (unsigned short)(r >> 16);
}

// round fp32 to bf16 precision, keep as fp32 (matches MFMA-bf16 numerics)
static __device__ __forceinline__ float bfr(float x) {
    union { float f; uint32_t u; } v; v.f = x;
    uint32_t r = (v.u + 0x7FFFu + ((v.u >> 16) & 1u)) & 0xFFFF0000u;
    union { uint32_t u; float f; } o; o.u = r;
    return o.f;
}

// expand 8 bits -> 8 packed bf16 {0.0, 1.0}.
static __device__ __forceinline__ short8 expand8(uint32_t B) {
    uint64_t S = ((uint64_t)B * 0x8040201008040201ull >> 7) & 0x0101010101010101ull;
    uint32_t lo = (uint32_t)S;          // bytes {b7,b6,b5,b4}
    uint32_t hi = (uint32_t)(S >> 32);  // bytes {b3,b2,b1,b0}
    union { uint32_t u[4]; short8 s; } r;
    r.u[0] = ((hi >> 24) | (((hi >> 16) & 0xFFu) << 16)) * 0x3F80u;  // e0,e1
    r.u[1] = (((hi >> 8) & 0xFFu) | ((hi & 0xFFu) << 16)) * 0x3F80u; // e2,e3
    r.u[2] = ((lo >> 24) | (((lo >> 16) & 0xFFu) << 16)) * 0x3F80u;  // e4,e5
    r.u[3] = (((lo >> 8) & 0xFFu) | ((lo & 0xFFu) << 16)) * 0x3F80u; // e6,e7
    return r.s;
}

// async global->LDS, 16 B per lane. LDS dest must be (wave-uniform base + lane*16);
// all call sites satisfy this by construction. Global src is per-lane arbitrary.
static __device__ __forceinline__ void gl_lds16(const void* g, void* l) {
    __builtin_amdgcn_global_load_lds(
        (const __attribute__((address_space(1))) uint32_t*)g,
        (__attribute__((address_space(3))) uint32_t*)l, 16, 0, 0);
}

// ---- prepass: adj int32 -> bitmask. 4096 blocks x 256 (wave = half a row). ----
__global__ __launch_bounds__(256) void k_adjbits(const int* __restrict__ adj,
                                                 uint32_t* __restrict__ adjb) {
    int t = threadIdx.x, lane = t & 63;
    int wv = blockIdx.x * 4 + (t >> 6);           // 0..16383
    int row = wv >> 1, half = wv & 1;
    const int4* p = reinterpret_cast<const int4*>(adj + (size_t)row * 8192 + half * 4096) + lane;
    uint32_t* ob = adjb + (size_t)row * 256 + half * 128;
    #pragma unroll 4
    for (int kk = 0; kk < 16; kk++) {
        int4 v = p[kk * 64];
        uint32_t nib = (v.x != 0 ? 1u : 0u) | (v.y != 0 ? 2u : 0u) |
                       (v.z != 0 ? 4u : 0u) | (v.w != 0 ? 8u : 0u);
        uint32_t q = nib | (((uint32_t)__shfl_xor((int)nib, 1)) << 4);
        q |= ((uint32_t)__shfl_xor((int)q, 2)) << 8;
        q |= ((uint32_t)__shfl_xor((int)q, 4)) << 16;
        if ((lane & 7) == 0) ob[kk * 8 + (lane >> 3)] = q;
    }
}

// ---- h = F@W+b, w = exp(h.a2w+a2b), emit fragment-major whB ----
__global__ __launch_bounds__(256) void k_hW(const float* __restrict__ F,
                                            const float* __restrict__ W,
                                            const float* __restrict__ bvec,
                                            const float* __restrict__ a2w,
                                            const float* __restrict__ a2b,
                                            unsigned short* __restrict__ whB) {
    __shared__ float Fs[32 * 256];     // 32 KB
    __shared__ float Ws[64 * 128];     // 32 KB (one kt-chunk of W)
    __shared__ float bs[128], aws[128], wls[32];
    __shared__ float ab_s;

    int t = threadIdx.x;
    int row = t >> 3, g = t & 7;
    int ig = blockIdx.x, j0 = ig * 32;

    if (t < 128) { bs[t] = bvec[t]; aws[t] = a2w[t]; }
    if (t == 0) ab_s = a2b[0];

    #pragma unroll
    for (int i = 0; i < 8; i++) {
        int flat = t + 256 * i;                   // float4 index
        int fr = flat >> 6, fp_ = (flat & 63) << 2;
        float4 v = *reinterpret_cast<const float4*>(F + (size_t)(j0 + fr) * 256 + fp_);
        float4 o; o.x = bfr(v.x); o.y = bfr(v.y); o.z = bfr(v.z); o.w = bfr(v.w);
        *reinterpret_cast<float4*>(&Fs[fr * 256 + fp_]) = o;
    }

    float h[16];
    #pragma unroll
    for (int i = 0; i < 16; i++) h[i] = 0.0f;

    for (int kt = 0; kt < 4; kt++) {
        if (kt) __syncthreads();
        #pragma unroll
        for (int i = 0; i < 8; i++) {
            int flat = t + 256 * i;
            int wr = flat >> 5, wp = (flat & 31) << 2;
            float4 v = *reinterpret_cast<const float4*>(W + (size_t)(kt * 64 + wr) * 128 + wp);
            float4 o; o.x = bfr(v.x); o.y = bfr(v.y); o.z = bfr(v.z); o.w = bfr(v.w);
            *reinterpret_cast<float4*>(&Ws[wr * 128 + wp]) = o;
        }
        __syncthreads();
        for (int kk = 0; kk < 64; kk++) {
            float f = Fs[row * 256 + kt * 64 + kk];
            #pragma unroll
            for (int i = 0; i < 16; i++)
                h[i] += f * Ws[kk * 128 + g * 16 + i];
        }
    }

    float part = 0.0f;
    #pragma unroll
    for (int i = 0; i < 16; i++) {
        h[i] += bs[g * 16 + i];
        part += h[i] * aws[g * 16 + i];
    }
    part += __shfl_xor(part, 1);
    part += __shfl_xor(part, 2);
    part += __shfl_xor(part, 4);
    float wv = expf(fminf(fmaxf(part + ab_s, -60.0f), 60.0f));
    if (g == 0) wls[row] = wv;

    // whB record (ig,c): lane l=(kq,m), elem r holds B[k=ig*32+kq*8+r][c*16+m].
    int kq = row >> 3, r = row & 7;
    #pragma unroll
    for (int i = 0; i < 16; i++) {
        unsigned short u = f2bf(h[i] * wv);
        whB[((size_t)(ig * 9 + g) * 64 + kq * 16 + i) * 8 + r] = u;
    }
    __syncthreads();
    if (t < 64) {
        int m0 = t & 15, kq2 = t >> 4;
        uint4 val = make_uint4(0u, 0u, 0u, 0u);
        if (m0 == 0) {
            uint32_t u0 = (uint32_t)f2bf(wls[kq2 * 8 + 0]) | ((uint32_t)f2bf(wls[kq2 * 8 + 1]) << 16);
            uint32_t u1 = (uint32_t)f2bf(wls[kq2 * 8 + 2]) | ((uint32_t)f2bf(wls[kq2 * 8 + 3]) << 16);
            uint32_t u2 = (uint32_t)f2bf(wls[kq2 * 8 + 4]) | ((uint32_t)f2bf(wls[kq2 * 8 + 5]) << 16);
            uint32_t u3 = (uint32_t)f2bf(wls[kq2 * 8 + 6]) | ((uint32_t)f2bf(wls[kq2 * 8 + 7]) << 16);
            val = make_uint4(u0, u1, u2, u3);
        }
        *reinterpret_cast<uint4*>(whB + ((size_t)(ig * 9 + 8) * 64 + t) * 8) = val;
    }
}

// ---- KMAIN v9: LDS-staged, double-buffered ----
// 512 blocks (64 rowsets x 8 ksplits) x 4 waves; block = 128 rows x K-chunk 1024.
// Phase = K 128: stage 36 KB whB-chunk + 2 KB mask into LDS (global_load_lds,
// async, issued before compute of prev phase); compute = ds_read_b128 + MFMA.
// Wave: 32 rows, acc[2][9]. Per-wave partials -> P[wid][72][64] (no atomics).
__global__ __launch_bounds__(256) void k_agg(const uint32_t* __restrict__ adjb,
                                             const unsigned short* __restrict__ whB,
                                             float* __restrict__ P) {
    __shared__ __align__(16) unsigned short Bs[2][36 * 512];   // 2 x 36,864 B
    __shared__ __align__(16) uint32_t Ab[2][512];              // 2 x  2,048 B

    int t = threadIdx.x;
    int w = t >> 6, lane = t & 63;
    int m = lane & 15, kq = lane >> 4;
    int blk = blockIdx.x;
    int bigrs = blk >> 3, ksplit = blk & 7;       // 64 rowsets x 8 ksplits
    int rb = bigrs * 128;
    int w32 = w * 32;
    uint32_t sh = (uint32_t)kq * 8;

    float4v acc[2][9];
    #pragma unroll
    for (int s = 0; s < 2; s++)
        for (int c = 0; c < 9; c++) acc[s][c] = (float4v)0.0f;

    auto stage = [&](int ph, int b) {
        // B: records [base_ig*9, base_ig*9+36), contiguous 36,864 B
        const unsigned short* gB = whB + (size_t)(ksplit * 32 + ph * 4) * 9 * 512;
        #pragma unroll
        for (int s = 0; s < 9; s++)
            gl_lds16(gB + (size_t)(s * 256 + t) * 8, &Bs[b][(s * 256 + t) * 8]);
        // A: 128 rows x 4 dwords (16 B) of mask for this phase (waves 0-1 only)
        if (t < 128)
            gl_lds16(adjb + (size_t)(rb + t) * 256 + ksplit * 32 + ph * 4, &Ab[b][t * 4]);
    };

    stage(0, 0);
    __syncthreads();

    for (int ph = 0; ph < 8; ph++) {
        int b = ph & 1;
        if (ph < 7) stage(ph + 1, b ^ 1);         // async, lands by the barrier below
        const unsigned short* bs = &Bs[b][0];
        const uint32_t* ab = &Ab[b][0];
        #pragma unroll
        for (int i4 = 0; i4 < 4; i4++) {
            uint32_t U0 = ab[(w32 + m) * 4 + i4];
            uint32_t U1 = ab[(w32 + 16 + m) * 4 + i4];
            short8 af0 = expand8((U0 >> sh) & 0xFFu);
            short8 af1 = expand8((U1 >> sh) & 0xFFu);
            #pragma unroll
            for (int c = 0; c < 9; c++) {
                short8 bf = *reinterpret_cast<const short8*>(&bs[(i4 * 9 + c) * 512 + lane * 8]);
                acc[0][c] = __builtin_amdgcn_mfma_f32_16x16x32_bf16(af0, bf, acc[0][c], 0, 0, 0);
                acc[1][c] = __builtin_amdgcn_mfma_f32_16x16x32_bf16(af1, bf, acc[1][c], 0, 0, 0);
            }
        }
        __syncthreads();                           // drains vmcnt -> next buf ready
    }

    int wid = blk * 4 + w;                        // 0..2047
    float* o = P + (size_t)wid * 4608 + lane;
    #pragma unroll
    for (int s = 0; s < 2; s++)
        for (int c = 0; c < 9; c++)
            for (int rr = 0; rr < 4; rr++)
                o[((s * 9 + c) * 4 + rr) * 64] = acc[s][c][rr];
}

// ---- reduce 8 ksplit-partials + divide. 256 blocks (one 32-row rowset each). ----
__global__ __launch_bounds__(256) void k_epi(const float* __restrict__ P,
                                             float* __restrict__ out) {
    __shared__ float den[32];
    int t = threadIdx.x;
    int g = blockIdx.x;                           // 32-row rowset
    int big = g >> 2, w = g & 3;

    float r[18];
    #pragma unroll
    for (int i = 0; i < 18; i++) {
        int p = t + 256 * i;
        float s = 0.0f;
        #pragma unroll
        for (int ks = 0; ks < 8; ks++)
            s += P[(size_t)((big * 8 + ks) * 4 + w) * 4608 + p];
        r[i] = s;
        int instr = p >> 6, lane = p & 63;
        int sc = instr >> 2, rr = instr & 3;
        int c = sc % 9, ss = sc / 9;
        int m = lane & 15, kq = lane >> 4;
        if (c == 8 && m == 0) den[ss * 16 + kq * 4 + rr] = s;
    }
    __syncthreads();
    #pragma unroll
    for (int i = 0; i < 18; i++) {
        int p = t + 256 * i;
        int instr = p >> 6, lane = p & 63;
        int sc = instr >> 2, rr = instr & 3;
        int c = sc % 9, ss = sc / 9;
        int m = lane & 15, kq = lane >> 4;
        if (c < 8) {
            int jl = ss * 16 + kq * 4 + rr;
            out[((size_t)(g * 32 + jl)) * 128 + c * 16 + m] = r[i] / den[jl];
        }
    }
}

extern "C" void kernel_launch(void* const* d_in, const int* in_sizes, int n_in,
                              void* d_out, int out_size, void* d_ws, size_t ws_size,
                              hipStream_t stream) {
    const float* F   = (const float*)d_in[0];     // [8192][256]
    const int*   adj = (const int*)d_in[1];       // [8192][8192] 0/1
    const float* W   = (const float*)d_in[2];     // [256][128]
    const float* bv  = (const float*)d_in[3];     // [128]
    const float* a2w = (const float*)d_in[6];     // [128]  (a1 cancels; d_in[4],[5] unused)
    const float* a2b = (const float*)d_in[7];     // [1]
    float* out = (float*)d_out;                   // [8192][128]

    char* ws = (char*)d_ws;
    unsigned short* whB  = (unsigned short*)(ws);            //  2,359,296 B
    uint32_t*       adjb = (uint32_t*)(ws + 2359296);        //  8,388,608 B
    float*          P    = (float*)(ws + 10747904);          // 37,748,736 B (2048 x 4608 fp32)
                                                             // total 48,496,640

    k_hW<<<256, 256, 0, stream>>>(F, W, bv, a2w, a2b, whB);
    k_adjbits<<<4096, 256, 0, stream>>>(adj, adjb);
    k_agg<<<512, 256, 0, stream>>>(adjb, whB, P);
    k_epi<<<256, 256, 0, stream>>>(P, out);
}